// Round 17
// baseline (236.027 us; speedup 1.0000x reference)
//
#include <hip/hip_runtime.h>
#include <hip/hip_bf16.h>
#include <stdint.h>

#define B_ 8
#define S_ 2048
#define H_ 512
#define P_ 16
#define K_ 256
#define M_TOT (B_*S_)      // 16384
#define KCAT (P_*K_)       // 4096

typedef short bf8v __attribute__((ext_vector_type(8)));   // 8 x bf16 (MFMA operand)
typedef float f4v  __attribute__((ext_vector_type(4)));   // MFMA accumulator

// ---- device-global scratch (recomputed from inputs on every call) ----
__device__ __align__(16) unsigned short g_hidden[M_TOT*H_];        // bf16 [m][h]
__device__ __align__(16) unsigned short g_w1t[P_*K_*H_];           // bf16 [n=p*256+k][h]
__device__ __align__(16) unsigned short g_w2cat[H_*KCAT];          // bf16 [h][p*256+k]
__device__ __align__(16) unsigned short g_mid[(size_t)M_TOT*KCAT]; // bf16 [m][p*256+k]

// d_ws layout: [0..127] raw logits (B*P), [128..4223] bias1 partials (embed@w1)

__device__ __forceinline__ unsigned short f2bf(float x){
  unsigned int u = __builtin_bit_cast(unsigned int, x);
  u += 0x7fffu + ((u >> 16) & 1u);              // round-to-nearest-even
  return (unsigned short)(u >> 16);
}

__device__ __forceinline__ unsigned int pk2bf(float x, float y){
  return ((unsigned int)f2bf(y) << 16) | (unsigned int)f2bf(x);
}

// tanh-approx GELU fused with prob scale: prob*x*(1 - 1/(1+e^{2c(x+0.044715x^3)}))
__device__ __forceinline__ float gelu_prob(float x, float prob){
  float x2 = x*x;
  float t1 = 0.044715f*x;
  float u2 = fmaf(t1, x2, x);                   // x + 0.044715 x^3
  float e  = __expf(1.5957691216f*u2);          // e^{2*0.79788456*u2}
  float r  = __builtin_amdgcn_rcpf(e + 1.0f);
  float px = prob*x;
  return fmaf(-px, r, px);                      // px*(1-r)
}

__device__ __forceinline__ void gll16(const unsigned short* src, unsigned short* lds){
  __builtin_amdgcn_global_load_lds(
      (const __attribute__((address_space(1))) unsigned int*)src,
      (__attribute__((address_space(3))) unsigned int*)lds,
      16, 0, 0);
}

// inline 16-wide softmax from raw logit sums
__device__ __forceinline__ void softmax16(const float* __restrict__ logits,
                                          const float* __restrict__ head_b,
                                          int b, float* lg, float* inv){
  float mx = -1e30f;
  #pragma unroll
  for (int pp=0; pp<P_; ++pp){
    lg[pp] = logits[b*P_+pp]*(1.0f/S_) + head_b[pp];
    mx = fmaxf(mx, lg[pp]);
  }
  float ssum = 0.0f;
  #pragma unroll
  for (int pp=0; pp<P_; ++pp){ lg[pp] = __expf(lg[pp]-mx); ssum += lg[pp]; }
  *inv = __builtin_amdgcn_rcpf(ssum);
}

// ---------- merged pre-pass ----------
// bid <  2048 : w1 transpose -> g_w1t; bias1 partial atomics into ws[128..]
// bid <  4096 : w2 transpose -> g_w2cat
// bid >= 4096 : hidden fp32->bf16 + logits partial atomics into ws[0..127]
__global__ void prepass(const float* __restrict__ w1, const float* __restrict__ w2,
                        const float* __restrict__ embeds,
                        const float* __restrict__ hs, const float* __restrict__ head_w,
                        float* __restrict__ ws){
  __shared__ float t[32][33];
  if (blockIdx.x < 2048){
    const int tx = threadIdx.x & 31, ty = threadIdx.x >> 5;    // 32 x 8
    const int R = H_, C = K_;                    // nrt=16, nct=8
    int p = blockIdx.x >> 7, rem = blockIdx.x & 127;
    int rt = rem >> 3, ct = rem & 7;
    const float* ip = w1 + (size_t)p*R*C + (size_t)(rt*32 + ty)*C + ct*32 + tx;
    #pragma unroll
    for (int k=0;k<4;++k) t[ty + 8*k][tx] = ip[(size_t)8*k*C];
    __syncthreads();
    unsigned short* op = g_w1t + (size_t)p*R*C + (size_t)(ct*32 + ty)*R + rt*32 + tx;
    #pragma unroll
    for (int k=0;k<4;++k) op[(size_t)8*k*R] = f2bf(t[tx][ty + 8*k]);
    if (ty == 0){                                // fused bias1 partial
      float s = 0.0f;
      const float* ep = embeds + p*H_ + rt*32;
      #pragma unroll 8
      for (int hh=0; hh<32; ++hh) s = fmaf(ep[hh], t[hh][tx], s);
      atomicAdd(&ws[128 + p*K_ + ct*32 + tx], s);
    }
  } else if (blockIdx.x < 4096){
    const int tx = threadIdx.x & 31, ty = threadIdx.x >> 5;
    const int bid = blockIdx.x - 2048;
    const int R = K_, C = H_;                    // nrt=8, nct=16
    int p = bid >> 7, rem = bid & 127;
    int rt = rem >> 4, ct = rem & 15;
    const float* ip = w2 + (size_t)p*R*C + (size_t)(rt*32 + ty)*C + ct*32 + tx;
    #pragma unroll
    for (int k=0;k<4;++k) t[ty + 8*k][tx] = ip[(size_t)8*k*C];
    __syncthreads();
    unsigned short* op = g_w2cat + (size_t)(ct*32 + ty)*KCAT + p*K_ + rt*32 + tx;
    #pragma unroll
    for (int k=0;k<4;++k) op[(size_t)8*k*KCAT] = f2bf(t[tx][ty + 8*k]);
  } else {
    const int row0 = (blockIdx.x - 4096) * 64;
    const int b = row0 >> 11;
    const int tid = threadIdx.x;
    const int tx = tid & 127, ty = tid >> 7;
    const float4* src = (const float4*)(hs + (size_t)row0*H_) + tx;
    uint2* dst = (uint2*)g_hidden + (size_t)row0*(H_/4) + tx;
    float4 s = {0.f,0.f,0.f,0.f};
    for (int r = ty; r < 64; r += 2){
      float4 v = src[(size_t)r*128];
      s.x += v.x; s.y += v.y; s.z += v.z; s.w += v.w;
      uint2 o = { pk2bf(v.x, v.y), pk2bf(v.z, v.w) };
      dst[(size_t)r*128] = o;
    }
    __shared__ float4 red[256];
    red[tid] = s;
    __syncthreads();
    if (ty == 0){                                // threads 0..127
      float4 a = red[tx], c = red[tx+128];
      float4 sf = { a.x+c.x, a.y+c.y, a.z+c.z, a.w+c.w };
      const float4* hw4 = (const float4*)head_w;
      float lp[P_];
      #pragma unroll
      for (int pp=0; pp<P_; ++pp){
        float4 hv = hw4[pp*128 + tx];
        lp[pp] = sf.x*hv.x + sf.y*hv.y + sf.z*hv.z + sf.w*hv.w;
      }
      #pragma unroll
      for (int off=32; off; off>>=1)
        #pragma unroll
        for (int pp=0; pp<P_; ++pp) lp[pp] += __shfl_down(lp[pp], off);
      if ((tid & 63) == 0){
        #pragma unroll
        for (int pp=0; pp<P_; ++pp) atomicAdd(&ws[b*P_+pp], lp[pp]);
      }
    }
  }
}

// ================= GEMM building blocks (BK=64) =================
// LDS tiles [row][64k] bf16 (128B rows), XOR-swizzled: byte ^= (row&7)<<4;
// linear LDS dest + inverse-swizzled per-lane global source (rule #21).

__device__ __forceinline__ void stage128(unsigned short* dst, const unsigned short* gsrc,
                                         int strideShorts, int koff, int tid){
  #pragma unroll
  for (int s = 0; s < 4; ++s){                   // 128x64 tile, 256 thr, 4x16B each
    const int o   = (s*256 + tid)*8;             // shorts offset in tile
    const int row = o >> 6;                      // 64 shorts/row
    const int ku  = (o & 63) >> 3;               // 16B unit within row
    const int sku = ku ^ (row & 7);
    gll16(gsrc + (size_t)row*strideShorts + koff + sku*8, dst + o);
  }
}

__device__ __forceinline__ void kcompute(const unsigned short* Ab, const unsigned short* Bb,
    int rowA0, int rowB0, int l15, int lhi, f4v acc[4][4]){
  #pragma unroll
  for (int ksub=0; ksub<2; ++ksub){
    const int kb = ksub*64 + lhi*16;             // byte offset in 128B row
    bf8v aF[4], bF[4];
    #pragma unroll
    for (int t=0; t<4; ++t){
      const int ra = rowA0 + t*16 + l15;
      aF[t] = *(const bf8v*)((const char*)Ab + ra*128 + (kb ^ ((ra&7)<<4)));
      const int rb = rowB0 + t*16 + l15;
      bF[t] = *(const bf8v*)((const char*)Bb + rb*128 + (kb ^ ((rb&7)<<4)));
    }
    __builtin_amdgcn_s_setprio(1);
    #pragma unroll
    for (int mt=0; mt<4; ++mt)
      #pragma unroll
      for (int nt=0; nt<4; ++nt)
        acc[mt][nt] = __builtin_amdgcn_mfma_f32_16x16x32_bf16(aF[mt], bF[nt], acc[mt][nt], 0,0,0);
    __builtin_amdgcn_s_setprio(0);
  }
}

// ---------- layer 1: M=16384, N=4096 (n=p*256+k), K=512 ----------
// BM=BN=128, BK=64, 256 thr = 4 waves (2M x 2N), wave 64x64, acc[4][4].
// Dbuf 64KB + counted-vmcnt 2-phase (r12-l2's proven loop); 2 blocks/CU.
// Epilogue bounce (128x136 shorts = 34.8KB) reuses stage LDS after final barrier.
__global__ __launch_bounds__(256, 2) void l1_kernel(const float* __restrict__ ws,
                                                   const float* __restrict__ head_b,
                                                   const float* __restrict__ b1){
  __shared__ __align__(16) unsigned short lds[4*128*64];  // 64 KiB: A0,A1,B0,B1
  const int bid = blockIdx.x;
  const int xcd = bid & 7, i = bid >> 3;         // i in [0,512)
  const int n0 = (xcd*4 + (i&3)) * 128;          // 4 n-tiles/XCD (L2-resident B)
  const int m0 = (i >> 2) * 128;
  const int p = n0 >> 8;
  const int b = m0 >> 11;
  const int tid = threadIdx.x, w = tid >> 6, lane = tid & 63;
  const int wm = w >> 1, wn = w & 1, l15 = lane & 15, lhi = lane >> 4;
  const unsigned short* gA = g_hidden + (size_t)m0 * H_;
  const unsigned short* gB = g_w1t + (size_t)n0 * H_;

  f4v acc[4][4];
  #pragma unroll
  for (int a=0;a<4;++a)
    #pragma unroll
    for (int c=0;c<4;++c) acc[a][c] = {0.f,0.f,0.f,0.f};

  stage128(lds + 0,     gA, H_, 0, tid);         // tile 0 -> buf0
  stage128(lds + 16384, gB, H_, 0, tid);
  for (int kt = 0; kt < 8; ++kt){
    const int cur = kt & 1;
    if (kt < 7){                                  // issue tile kt+1 into buf^1
      stage128(lds + (cur ? 0 : 8192),         gA, H_, (kt+1)*64, tid);
      stage128(lds + 16384 + (cur ? 0 : 8192), gB, H_, (kt+1)*64, tid);
      asm volatile("s_waitcnt vmcnt(8)" ::: "memory");   // current tile landed; next in flight
    } else {
      asm volatile("s_waitcnt vmcnt(0)" ::: "memory");
    }
    __builtin_amdgcn_s_barrier();                 // all waves: current tile in LDS
    kcompute(lds + (cur ? 8192 : 0), lds + 16384 + (cur ? 8192 : 0),
             wm*64, wn*64, l15, lhi, acc);
    __builtin_amdgcn_s_barrier();                 // reads done before buf reuse next iter
  }

  // inline softmax -> prob for this block's expert p
  float lg[P_], inv;
  softmax16(ws, head_b, b, lg, &inv);
  const float prob = lg[p] * inv;

  // epilogue: gelu*prob -> bf16 -> pad-136 LDS bounce -> 16B stores
  #pragma unroll
  for (int nt=0; nt<4; ++nt){
    const int col = wn*64 + nt*16 + l15;
    const float bias = ws[128 + n0 + col] + b1[n0 + col];
    #pragma unroll
    for (int mt=0; mt<4; ++mt){
      const int r0 = wm*64 + mt*16 + lhi*4;
      unsigned int u01 = pk2bf(gelu_prob(acc[mt][nt][0] + bias, prob),
                               gelu_prob(acc[mt][nt][1] + bias, prob));
      unsigned int u23 = pk2bf(gelu_prob(acc[mt][nt][2] + bias, prob),
                               gelu_prob(acc[mt][nt][3] + bias, prob));
      lds[(r0+0)*136 + col] = (unsigned short)(u01 & 0xffffu);
      lds[(r0+1)*136 + col] = (unsigned short)(u01 >> 16);
      lds[(r0+2)*136 + col] = (unsigned short)(u23 & 0xffffu);
      lds[(r0+3)*136 + col] = (unsigned short)(u23 >> 16);
    }
  }
  __syncthreads();
  const int cc = tid & 15, rr = tid >> 4;        // 16 cols x 16 rows per sweep
  #pragma unroll
  for (int pass=0; pass<8; ++pass){
    const int row = pass*16 + rr;
    bf8v vv = *(const bf8v*)&lds[row*136 + cc*8];
    *(bf8v*)&g_mid[(size_t)(m0+row)*KCAT + n0 + cc*8] = vv;
  }
}

// ---------- layer 2: out = mid @ w2cat^T + probs.b2 : M=16384, N=512, K=4096 ----------
// BM=BN=128, BK=64, 256 thr, wave 64x64. Dbuf 64KB, counted-vmcnt 2-phase (r12).
__global__ __launch_bounds__(256, 2) void l2_kernel(float* __restrict__ out,
                                                   const float* __restrict__ b2,
                                                   const float* __restrict__ ws,
                                                   const float* __restrict__ head_b){
  __shared__ __align__(16) unsigned short lds[4*128*64];  // 64 KiB: A0,A1,B0,B1
  const int bid = blockIdx.x;
  const int xcd = bid & 7, i = bid >> 3;         // i in [0,64)
  const int n0 = (i & 3) * 128;
  const int m0 = (xcd*16 + (i >> 2)) * 128;
  const int b = m0 >> 11;
  const int tid = threadIdx.x, w = tid >> 6, lane = tid & 63;
  const int wm = w >> 1, wn = w & 1, l15 = lane & 15, lhi = lane >> 4;
  const unsigned short* gA = g_mid + (size_t)m0 * KCAT;
  const unsigned short* gB = g_w2cat + (size_t)n0 * KCAT;

  f4v acc[4][4];
  #pragma unroll
  for (int a=0;a<4;++a)
    #pragma unroll
    for (int c=0;c<4;++c) acc[a][c] = {0.f,0.f,0.f,0.f};

  stage128(lds + 0,     gA, KCAT, 0, tid);       // tile 0 -> buf0
  stage128(lds + 16384, gB, KCAT, 0, tid);
  for (int kt = 0; kt < 64; ++kt){
    const int cur = kt & 1;
    if (kt < 63){                                 // issue tile kt+1 into buf^1
      stage128(lds + (cur ? 0 : 8192),         gA, KCAT, (kt+1)*64, tid);
      stage128(lds + 16384 + (cur ? 0 : 8192), gB, KCAT, (kt+1)*64, tid);
      asm volatile("s_waitcnt vmcnt(8)" ::: "memory");   // current tile landed; next in flight
    } else {
      asm volatile("s_waitcnt vmcnt(0)" ::: "memory");
    }
    __builtin_amdgcn_s_barrier();                 // all waves: current tile in LDS
    kcompute(lds + (cur ? 8192 : 0), lds + 16384 + (cur ? 8192 : 0),
             wm*64, wn*64, l15, lhi, acc);
    __builtin_amdgcn_s_barrier();                 // reads done before buf reuse next iter
  }

  // inline softmax -> full prob vector; bias2w inline
  float lg[P_], inv;
  softmax16(ws, head_b, b, lg, &inv);

  #pragma unroll
  for (int nt=0; nt<4; ++nt){
    const int col = n0 + wn*64 + nt*16 + l15;
    float extra = 0.0f;
    #pragma unroll
    for (int pp=0; pp<P_; ++pp) extra = fmaf(lg[pp]*inv, b2[pp*H_ + col], extra);
    #pragma unroll
    for (int mt=0; mt<4; ++mt){
      #pragma unroll
      for (int j=0;j<4;++j){
        const int row = m0 + wm*64 + mt*16 + lhi*4 + j;
        out[(size_t)row*H_ + col] = acc[mt][nt][j] + extra;
      }
    }
  }
}

extern "C" void kernel_launch(void* const* d_in, const int* in_sizes, int n_in,
                              void* d_out, int out_size, void* d_ws, size_t ws_size,
                              hipStream_t stream){
  const float* hidden = (const float*)d_in[0];
  const float* head_w = (const float*)d_in[1];
  const float* head_b = (const float*)d_in[2];
  const float* embeds = (const float*)d_in[3];
  const float* w1     = (const float*)d_in[4];
  const float* b1     = (const float*)d_in[5];
  const float* w2     = (const float*)d_in[6];
  const float* b2     = (const float*)d_in[7];
  float* out = (float*)d_out;
  float* ws  = (float*)d_ws;   // [0..127] logits, [128..4223] bias1 partials
  (void)in_sizes; (void)n_in; (void)out_size; (void)ws_size;

  (void)hipMemsetAsync(ws, 0, (B_*P_ + P_*K_)*sizeof(float), stream);
  prepass  <<<4096 + M_TOT/64, 256, 0, stream>>>(w1, w2, embeds, hidden, head_w, ws);
  l1_kernel<<<4096, 256, 0, stream>>>(ws, head_b, b1);
  l2_kernel<<<512, 256, 0, stream>>>(out, b2, ws, head_b);
}

// Round 18
// 233.164 us; speedup vs baseline: 1.0123x; 1.0123x over previous
//
#include <hip/hip_runtime.h>
#include <hip/hip_bf16.h>
#include <stdint.h>

#define B_ 8
#define S_ 2048
#define H_ 512
#define P_ 16
#define K_ 256
#define M_TOT (B_*S_)      // 16384
#define KCAT (P_*K_)       // 4096

typedef short bf8v __attribute__((ext_vector_type(8)));   // 8 x bf16 (MFMA operand)
typedef float f4v  __attribute__((ext_vector_type(4)));   // MFMA accumulator

// ---- device-global scratch (recomputed from inputs on every call) ----
__device__ __align__(16) unsigned short g_hidden[M_TOT*H_];        // bf16 [m][h]
__device__ __align__(16) unsigned short g_w1t[P_*K_*H_];           // bf16 [n=p*256+k][h]
__device__ __align__(16) unsigned short g_w2cat[H_*KCAT];          // bf16 [h][p*256+k]
__device__ __align__(16) unsigned short g_mid[(size_t)M_TOT*KCAT]; // bf16 [m][p*256+k]

// d_ws layout: [0..127] raw logits (B*P), [128..4223] bias1 partials (embed@w1)

__device__ __forceinline__ unsigned short f2bf(float x){
  unsigned int u = __builtin_bit_cast(unsigned int, x);
  u += 0x7fffu + ((u >> 16) & 1u);              // round-to-nearest-even
  return (unsigned short)(u >> 16);
}

__device__ __forceinline__ unsigned int pk2bf(float x, float y){
  return ((unsigned int)f2bf(y) << 16) | (unsigned int)f2bf(x);
}

// tanh-approx GELU fused with prob scale: prob*x*(1 - 1/(1+e^{2c(x+0.044715x^3)}))
__device__ __forceinline__ float gelu_prob(float x, float prob){
  float x2 = x*x;
  float t1 = 0.044715f*x;
  float u2 = fmaf(t1, x2, x);                   // x + 0.044715 x^3
  float e  = __expf(1.5957691216f*u2);          // e^{2*0.79788456*u2}
  float r  = __builtin_amdgcn_rcpf(e + 1.0f);
  float px = prob*x;
  return fmaf(-px, r, px);                      // px*(1-r)
}

__device__ __forceinline__ void gll16(const unsigned short* src, unsigned short* lds){
  __builtin_amdgcn_global_load_lds(
      (const __attribute__((address_space(1))) unsigned int*)src,
      (__attribute__((address_space(3))) unsigned int*)lds,
      16, 0, 0);
}

// inline 16-wide softmax from raw logit sums
__device__ __forceinline__ void softmax16(const float* __restrict__ logits,
                                          const float* __restrict__ head_b,
                                          int b, float* lg, float* inv){
  float mx = -1e30f;
  #pragma unroll
  for (int pp=0; pp<P_; ++pp){
    lg[pp] = logits[b*P_+pp]*(1.0f/S_) + head_b[pp];
    mx = fmaxf(mx, lg[pp]);
  }
  float ssum = 0.0f;
  #pragma unroll
  for (int pp=0; pp<P_; ++pp){ lg[pp] = __expf(lg[pp]-mx); ssum += lg[pp]; }
  *inv = __builtin_amdgcn_rcpf(ssum);
}

// ---------- merged pre-pass ----------
// bid <  2048 : w1 transpose -> g_w1t; bias1 partial atomics into ws[128..]
// bid <  4096 : w2 transpose -> g_w2cat
// bid >= 4096 : hidden fp32->bf16 + logits partial atomics into ws[0..127]
__global__ void prepass(const float* __restrict__ w1, const float* __restrict__ w2,
                        const float* __restrict__ embeds,
                        const float* __restrict__ hs, const float* __restrict__ head_w,
                        float* __restrict__ ws){
  __shared__ float t[32][33];
  if (blockIdx.x < 2048){
    const int tx = threadIdx.x & 31, ty = threadIdx.x >> 5;    // 32 x 8
    const int R = H_, C = K_;                    // nrt=16, nct=8
    int p = blockIdx.x >> 7, rem = blockIdx.x & 127;
    int rt = rem >> 3, ct = rem & 7;
    const float* ip = w1 + (size_t)p*R*C + (size_t)(rt*32 + ty)*C + ct*32 + tx;
    #pragma unroll
    for (int k=0;k<4;++k) t[ty + 8*k][tx] = ip[(size_t)8*k*C];
    __syncthreads();
    unsigned short* op = g_w1t + (size_t)p*R*C + (size_t)(ct*32 + ty)*R + rt*32 + tx;
    #pragma unroll
    for (int k=0;k<4;++k) op[(size_t)8*k*R] = f2bf(t[tx][ty + 8*k]);
    if (ty == 0){                                // fused bias1 partial
      float s = 0.0f;
      const float* ep = embeds + p*H_ + rt*32;
      #pragma unroll 8
      for (int hh=0; hh<32; ++hh) s = fmaf(ep[hh], t[hh][tx], s);
      atomicAdd(&ws[128 + p*K_ + ct*32 + tx], s);
    }
  } else if (blockIdx.x < 4096){
    const int tx = threadIdx.x & 31, ty = threadIdx.x >> 5;
    const int bid = blockIdx.x - 2048;
    const int R = K_, C = H_;                    // nrt=8, nct=16
    int p = bid >> 7, rem = bid & 127;
    int rt = rem >> 4, ct = rem & 15;
    const float* ip = w2 + (size_t)p*R*C + (size_t)(rt*32 + ty)*C + ct*32 + tx;
    #pragma unroll
    for (int k=0;k<4;++k) t[ty + 8*k][tx] = ip[(size_t)8*k*C];
    __syncthreads();
    unsigned short* op = g_w2cat + (size_t)(ct*32 + ty)*KCAT + p*K_ + rt*32 + tx;
    #pragma unroll
    for (int k=0;k<4;++k) op[(size_t)8*k*KCAT] = f2bf(t[tx][ty + 8*k]);
  } else {
    const int row0 = (blockIdx.x - 4096) * 64;
    const int b = row0 >> 11;
    const int tid = threadIdx.x;
    const int tx = tid & 127, ty = tid >> 7;
    const float4* src = (const float4*)(hs + (size_t)row0*H_) + tx;
    uint2* dst = (uint2*)g_hidden + (size_t)row0*(H_/4) + tx;
    float4 s = {0.f,0.f,0.f,0.f};
    for (int r = ty; r < 64; r += 2){
      float4 v = src[(size_t)r*128];
      s.x += v.x; s.y += v.y; s.z += v.z; s.w += v.w;
      uint2 o = { pk2bf(v.x, v.y), pk2bf(v.z, v.w) };
      dst[(size_t)r*128] = o;
    }
    __shared__ float4 red[256];
    red[tid] = s;
    __syncthreads();
    if (ty == 0){                                // threads 0..127
      float4 a = red[tx], c = red[tx+128];
      float4 sf = { a.x+c.x, a.y+c.y, a.z+c.z, a.w+c.w };
      const float4* hw4 = (const float4*)head_w;
      float lp[P_];
      #pragma unroll
      for (int pp=0; pp<P_; ++pp){
        float4 hv = hw4[pp*128 + tx];
        lp[pp] = sf.x*hv.x + sf.y*hv.y + sf.z*hv.z + sf.w*hv.w;
      }
      #pragma unroll
      for (int off=32; off; off>>=1)
        #pragma unroll
        for (int pp=0; pp<P_; ++pp) lp[pp] += __shfl_down(lp[pp], off);
      if ((tid & 63) == 0){
        #pragma unroll
        for (int pp=0; pp<P_; ++pp) atomicAdd(&ws[b*P_+pp], lp[pp]);
      }
    }
  }
}

// ================= GEMM building blocks (BK=64) =================
// LDS tiles [row][64k] bf16 (128B rows), XOR-swizzled: byte ^= (row&7)<<4;
// linear LDS dest + inverse-swizzled per-lane global source (rule #21).

__device__ __forceinline__ void stage128(unsigned short* dst, const unsigned short* gsrc,
                                         int strideShorts, int koff, int tid){
  #pragma unroll
  for (int s = 0; s < 4; ++s){                   // 128x64 tile, 256 thr, 4x16B each
    const int o   = (s*256 + tid)*8;             // shorts offset in tile
    const int row = o >> 6;                      // 64 shorts/row
    const int ku  = (o & 63) >> 3;               // 16B unit within row
    const int sku = ku ^ (row & 7);
    gll16(gsrc + (size_t)row*strideShorts + koff + sku*8, dst + o);
  }
}

__device__ __forceinline__ void kcompute(const unsigned short* Ab, const unsigned short* Bb,
    int rowA0, int rowB0, int l15, int lhi, f4v acc[4][4]){
  #pragma unroll
  for (int ksub=0; ksub<2; ++ksub){
    const int kb = ksub*64 + lhi*16;             // byte offset in 128B row
    bf8v aF[4], bF[4];
    #pragma unroll
    for (int t=0; t<4; ++t){
      const int ra = rowA0 + t*16 + l15;
      aF[t] = *(const bf8v*)((const char*)Ab + ra*128 + (kb ^ ((ra&7)<<4)));
      const int rb = rowB0 + t*16 + l15;
      bF[t] = *(const bf8v*)((const char*)Bb + rb*128 + (kb ^ ((rb&7)<<4)));
    }
    __builtin_amdgcn_s_setprio(1);
    #pragma unroll
    for (int mt=0; mt<4; ++mt)
      #pragma unroll
      for (int nt=0; nt<4; ++nt)
        acc[mt][nt] = __builtin_amdgcn_mfma_f32_16x16x32_bf16(aF[mt], bF[nt], acc[mt][nt], 0,0,0);
    __builtin_amdgcn_s_setprio(0);
  }
}

// ---------- layer 1: M=16384, N=4096 (n=p*256+k), K=512 ----------
// BM=BN=128, BK=64, 256 thr = 4 waves (2M x 2N), wave 64x64, acc[4][4].
// Single-buffered 32KB stage; 34KB LDS total (pad-136 bounce) -> 4 blocks/CU.
// (r16 structure, measured 106us; occupancy is l1's binding constraint.)
__global__ __launch_bounds__(256, 4) void l1_kernel(const float* __restrict__ ws,
                                                   const float* __restrict__ head_b,
                                                   const float* __restrict__ b1){
  __shared__ __align__(16) unsigned short lds[128*136];   // 34816 B
  const int bid = blockIdx.x;
  const int xcd = bid & 7, i = bid >> 3;         // i in [0,512)
  const int n0 = (xcd*4 + (i&3)) * 128;          // 4 n-tiles/XCD (L2-resident B)
  const int m0 = (i >> 2) * 128;
  const int p = n0 >> 8;
  const int b = m0 >> 11;
  const int tid = threadIdx.x, w = tid >> 6, lane = tid & 63;
  const int wm = w >> 1, wn = w & 1, l15 = lane & 15, lhi = lane >> 4;
  const unsigned short* gA = g_hidden + (size_t)m0 * H_;
  const unsigned short* gB = g_w1t + (size_t)n0 * H_;

  f4v acc[4][4];
  #pragma unroll
  for (int a=0;a<4;++a)
    #pragma unroll
    for (int c=0;c<4;++c) acc[a][c] = {0.f,0.f,0.f,0.f};

  for (int kt = 0; kt < 8; ++kt){
    stage128(lds,        gA, H_, kt*64, tid);
    stage128(lds + 8192, gB, H_, kt*64, tid);
    __syncthreads();
    kcompute(lds, lds + 8192, wm*64, wn*64, l15, lhi, acc);
    __syncthreads();
  }

  // inline softmax -> prob for this block's expert p
  float lg[P_], inv;
  softmax16(ws, head_b, b, lg, &inv);
  const float prob = lg[p] * inv;

  // epilogue: gelu*prob -> bf16 -> pad-136 LDS bounce -> 16B stores
  #pragma unroll
  for (int nt=0; nt<4; ++nt){
    const int col = wn*64 + nt*16 + l15;
    const float bias = ws[128 + n0 + col] + b1[n0 + col];
    #pragma unroll
    for (int mt=0; mt<4; ++mt){
      const int r0 = wm*64 + mt*16 + lhi*4;
      unsigned int u01 = pk2bf(gelu_prob(acc[mt][nt][0] + bias, prob),
                               gelu_prob(acc[mt][nt][1] + bias, prob));
      unsigned int u23 = pk2bf(gelu_prob(acc[mt][nt][2] + bias, prob),
                               gelu_prob(acc[mt][nt][3] + bias, prob));
      lds[(r0+0)*136 + col] = (unsigned short)(u01 & 0xffffu);
      lds[(r0+1)*136 + col] = (unsigned short)(u01 >> 16);
      lds[(r0+2)*136 + col] = (unsigned short)(u23 & 0xffffu);
      lds[(r0+3)*136 + col] = (unsigned short)(u23 >> 16);
    }
  }
  __syncthreads();
  const int cc = tid & 15, rr = tid >> 4;        // 16 cols x 16 rows per sweep
  #pragma unroll
  for (int pass=0; pass<8; ++pass){
    const int row = pass*16 + rr;
    bf8v vv = *(const bf8v*)&lds[row*136 + cc*8];
    *(bf8v*)&g_mid[(size_t)(m0+row)*KCAT + n0 + cc*8] = vv;
  }
}

// ---------- layer 2: out = mid @ w2cat^T + probs.b2 : M=16384, N=512, K=4096 ----------
// BM=BN=128, BK=64, 256 thr, wave 64x64. Dbuf 64KB, counted-vmcnt 2-phase (r12).
// (Pipelining is l2's binding constraint: long K-loop amortizes, 2/CU suffices.)
__global__ __launch_bounds__(256, 2) void l2_kernel(float* __restrict__ out,
                                                   const float* __restrict__ b2,
                                                   const float* __restrict__ ws,
                                                   const float* __restrict__ head_b){
  __shared__ __align__(16) unsigned short lds[4*128*64];  // 64 KiB: A0,A1,B0,B1
  const int bid = blockIdx.x;
  const int xcd = bid & 7, i = bid >> 3;         // i in [0,64)
  const int n0 = (i & 3) * 128;
  const int m0 = (xcd*16 + (i >> 2)) * 128;
  const int b = m0 >> 11;
  const int tid = threadIdx.x, w = tid >> 6, lane = tid & 63;
  const int wm = w >> 1, wn = w & 1, l15 = lane & 15, lhi = lane >> 4;
  const unsigned short* gA = g_mid + (size_t)m0 * KCAT;
  const unsigned short* gB = g_w2cat + (size_t)n0 * KCAT;

  f4v acc[4][4];
  #pragma unroll
  for (int a=0;a<4;++a)
    #pragma unroll
    for (int c=0;c<4;++c) acc[a][c] = {0.f,0.f,0.f,0.f};

  stage128(lds + 0,     gA, KCAT, 0, tid);       // tile 0 -> buf0
  stage128(lds + 16384, gB, KCAT, 0, tid);
  for (int kt = 0; kt < 64; ++kt){
    const int cur = kt & 1;
    if (kt < 63){                                 // issue tile kt+1 into buf^1
      stage128(lds + (cur ? 0 : 8192),         gA, KCAT, (kt+1)*64, tid);
      stage128(lds + 16384 + (cur ? 0 : 8192), gB, KCAT, (kt+1)*64, tid);
      asm volatile("s_waitcnt vmcnt(8)" ::: "memory");   // current tile landed; next in flight
    } else {
      asm volatile("s_waitcnt vmcnt(0)" ::: "memory");
    }
    __builtin_amdgcn_s_barrier();                 // all waves: current tile in LDS
    kcompute(lds + (cur ? 8192 : 0), lds + 16384 + (cur ? 8192 : 0),
             wm*64, wn*64, l15, lhi, acc);
    __builtin_amdgcn_s_barrier();                 // reads done before buf reuse next iter
  }

  // inline softmax -> full prob vector; bias2w inline
  float lg[P_], inv;
  softmax16(ws, head_b, b, lg, &inv);

  #pragma unroll
  for (int nt=0; nt<4; ++nt){
    const int col = n0 + wn*64 + nt*16 + l15;
    float extra = 0.0f;
    #pragma unroll
    for (int pp=0; pp<P_; ++pp) extra = fmaf(lg[pp]*inv, b2[pp*H_ + col], extra);
    #pragma unroll
    for (int mt=0; mt<4; ++mt){
      #pragma unroll
      for (int j=0;j<4;++j){
        const int row = m0 + wm*64 + mt*16 + lhi*4 + j;
        out[(size_t)row*H_ + col] = acc[mt][nt][j] + extra;
      }
    }
  }
}

extern "C" void kernel_launch(void* const* d_in, const int* in_sizes, int n_in,
                              void* d_out, int out_size, void* d_ws, size_t ws_size,
                              hipStream_t stream){
  const float* hidden = (const float*)d_in[0];
  const float* head_w = (const float*)d_in[1];
  const float* head_b = (const float*)d_in[2];
  const float* embeds = (const float*)d_in[3];
  const float* w1     = (const float*)d_in[4];
  const float* b1     = (const float*)d_in[5];
  const float* w2     = (const float*)d_in[6];
  const float* b2     = (const float*)d_in[7];
  float* out = (float*)d_out;
  float* ws  = (float*)d_ws;   // [0..127] logits, [128..4223] bias1 partials
  (void)in_sizes; (void)n_in; (void)out_size; (void)ws_size;

  (void)hipMemsetAsync(ws, 0, (B_*P_ + P_*K_)*sizeof(float), stream);
  prepass  <<<4096 + M_TOT/64, 256, 0, stream>>>(w1, w2, embeds, hidden, head_w, ws);
  l1_kernel<<<4096, 256, 0, stream>>>(ws, head_b, b1);
  l2_kernel<<<512, 256, 0, stream>>>(out, b2, ws, head_b);
}

// Round 19
// 233.010 us; speedup vs baseline: 1.0129x; 1.0007x over previous
//
#include <hip/hip_runtime.h>
#include <hip/hip_bf16.h>
#include <stdint.h>

#define B_ 8
#define S_ 2048
#define H_ 512
#define P_ 16
#define K_ 256
#define M_TOT (B_*S_)      // 16384
#define KCAT (P_*K_)       // 4096
#define BPAD 132           // bounce row pitch (shorts): 66 dwords -> lhi groups at
                           // bank offsets {0,8,16,24} -> conflict-free epilogue writes

typedef short bf8v __attribute__((ext_vector_type(8)));   // 8 x bf16 (MFMA operand)
typedef float f4v  __attribute__((ext_vector_type(4)));   // MFMA accumulator

// ---- device-global scratch (recomputed from inputs on every call) ----
__device__ __align__(16) unsigned short g_hidden[M_TOT*H_];        // bf16 [m][h]
__device__ __align__(16) unsigned short g_w1t[P_*K_*H_];           // bf16 [n=p*256+k][h]
__device__ __align__(16) unsigned short g_w2cat[H_*KCAT];          // bf16 [h][p*256+k]
__device__ __align__(16) unsigned short g_mid[(size_t)M_TOT*KCAT]; // bf16 [m][p*256+k]

// d_ws layout: [0..127] raw logits (B*P), [128..4223] bias1 partials (embed@w1)

__device__ __forceinline__ unsigned short f2bf(float x){
  unsigned int u = __builtin_bit_cast(unsigned int, x);
  u += 0x7fffu + ((u >> 16) & 1u);              // round-to-nearest-even
  return (unsigned short)(u >> 16);
}

__device__ __forceinline__ unsigned int pk2bf(float x, float y){
  return ((unsigned int)f2bf(y) << 16) | (unsigned int)f2bf(x);
}

// tanh-approx GELU fused with prob scale: prob*x*(1 - 1/(1+e^{2c(x+0.044715x^3)}))
__device__ __forceinline__ float gelu_prob(float x, float prob){
  float x2 = x*x;
  float t1 = 0.044715f*x;
  float u2 = fmaf(t1, x2, x);                   // x + 0.044715 x^3
  float e  = __expf(1.5957691216f*u2);          // e^{2*0.79788456*u2}
  float r  = __builtin_amdgcn_rcpf(e + 1.0f);
  float px = prob*x;
  return fmaf(-px, r, px);                      // px*(1-r)
}

__device__ __forceinline__ void gll16(const unsigned short* src, unsigned short* lds){
  __builtin_amdgcn_global_load_lds(
      (const __attribute__((address_space(1))) unsigned int*)src,
      (__attribute__((address_space(3))) unsigned int*)lds,
      16, 0, 0);
}

// inline 16-wide softmax from raw logit sums
__device__ __forceinline__ void softmax16(const float* __restrict__ logits,
                                          const float* __restrict__ head_b,
                                          int b, float* lg, float* inv){
  float mx = -1e30f;
  #pragma unroll
  for (int pp=0; pp<P_; ++pp){
    lg[pp] = logits[b*P_+pp]*(1.0f/S_) + head_b[pp];
    mx = fmaxf(mx, lg[pp]);
  }
  float ssum = 0.0f;
  #pragma unroll
  for (int pp=0; pp<P_; ++pp){ lg[pp] = __expf(lg[pp]-mx); ssum += lg[pp]; }
  *inv = __builtin_amdgcn_rcpf(ssum);
}

// ---------- merged pre-pass ----------
// bid <  2048 : w1 transpose -> g_w1t; bias1 partial atomics into ws[128..]
// bid <  4096 : w2 transpose -> g_w2cat
// bid >= 4096 : hidden fp32->bf16 + logits partial atomics into ws[0..127]
__global__ void prepass(const float* __restrict__ w1, const float* __restrict__ w2,
                        const float* __restrict__ embeds,
                        const float* __restrict__ hs, const float* __restrict__ head_w,
                        float* __restrict__ ws){
  __shared__ float t[32][33];
  if (blockIdx.x < 2048){
    const int tx = threadIdx.x & 31, ty = threadIdx.x >> 5;    // 32 x 8
    const int R = H_, C = K_;                    // nrt=16, nct=8
    int p = blockIdx.x >> 7, rem = blockIdx.x & 127;
    int rt = rem >> 3, ct = rem & 7;
    const float* ip = w1 + (size_t)p*R*C + (size_t)(rt*32 + ty)*C + ct*32 + tx;
    #pragma unroll
    for (int k=0;k<4;++k) t[ty + 8*k][tx] = ip[(size_t)8*k*C];
    __syncthreads();
    unsigned short* op = g_w1t + (size_t)p*R*C + (size_t)(ct*32 + ty)*R + rt*32 + tx;
    #pragma unroll
    for (int k=0;k<4;++k) op[(size_t)8*k*R] = f2bf(t[tx][ty + 8*k]);
    if (ty == 0){                                // fused bias1 partial
      float s = 0.0f;
      const float* ep = embeds + p*H_ + rt*32;
      #pragma unroll 8
      for (int hh=0; hh<32; ++hh) s = fmaf(ep[hh], t[hh][tx], s);
      atomicAdd(&ws[128 + p*K_ + ct*32 + tx], s);
    }
  } else if (blockIdx.x < 4096){
    const int tx = threadIdx.x & 31, ty = threadIdx.x >> 5;
    const int bid = blockIdx.x - 2048;
    const int R = K_, C = H_;                    // nrt=8, nct=16
    int p = bid >> 7, rem = bid & 127;
    int rt = rem >> 4, ct = rem & 15;
    const float* ip = w2 + (size_t)p*R*C + (size_t)(rt*32 + ty)*C + ct*32 + tx;
    #pragma unroll
    for (int k=0;k<4;++k) t[ty + 8*k][tx] = ip[(size_t)8*k*C];
    __syncthreads();
    unsigned short* op = g_w2cat + (size_t)(ct*32 + ty)*KCAT + p*K_ + rt*32 + tx;
    #pragma unroll
    for (int k=0;k<4;++k) op[(size_t)8*k*KCAT] = f2bf(t[tx][ty + 8*k]);
  } else {
    const int row0 = (blockIdx.x - 4096) * 64;
    const int b = row0 >> 11;
    const int tid = threadIdx.x;
    const int tx = tid & 127, ty = tid >> 7;
    const float4* src = (const float4*)(hs + (size_t)row0*H_) + tx;
    uint2* dst = (uint2*)g_hidden + (size_t)row0*(H_/4) + tx;
    float4 s = {0.f,0.f,0.f,0.f};
    for (int r = ty; r < 64; r += 2){
      float4 v = src[(size_t)r*128];
      s.x += v.x; s.y += v.y; s.z += v.z; s.w += v.w;
      uint2 o = { pk2bf(v.x, v.y), pk2bf(v.z, v.w) };
      dst[(size_t)r*128] = o;
    }
    __shared__ float4 red[256];
    red[tid] = s;
    __syncthreads();
    if (ty == 0){                                // threads 0..127
      float4 a = red[tx], c = red[tx+128];
      float4 sf = { a.x+c.x, a.y+c.y, a.z+c.z, a.w+c.w };
      const float4* hw4 = (const float4*)head_w;
      float lp[P_];
      #pragma unroll
      for (int pp=0; pp<P_; ++pp){
        float4 hv = hw4[pp*128 + tx];
        lp[pp] = sf.x*hv.x + sf.y*hv.y + sf.z*hv.z + sf.w*hv.w;
      }
      #pragma unroll
      for (int off=32; off; off>>=1)
        #pragma unroll
        for (int pp=0; pp<P_; ++pp) lp[pp] += __shfl_down(lp[pp], off);
      if ((tid & 63) == 0){
        #pragma unroll
        for (int pp=0; pp<P_; ++pp) atomicAdd(&ws[b*P_+pp], lp[pp]);
      }
    }
  }
}

// ================= GEMM building blocks (BK=64) =================
// LDS tiles [row][64k] bf16 (128B rows), XOR-swizzled: byte ^= (row&7)<<4;
// linear LDS dest + inverse-swizzled per-lane global source (rule #21).

__device__ __forceinline__ void stage128(unsigned short* dst, const unsigned short* gsrc,
                                         int strideShorts, int koff, int tid){
  #pragma unroll
  for (int s = 0; s < 4; ++s){                   // 128x64 tile, 256 thr, 4x16B each
    const int o   = (s*256 + tid)*8;             // shorts offset in tile
    const int row = o >> 6;                      // 64 shorts/row
    const int ku  = (o & 63) >> 3;               // 16B unit within row
    const int sku = ku ^ (row & 7);
    gll16(gsrc + (size_t)row*strideShorts + koff + sku*8, dst + o);
  }
}

__device__ __forceinline__ void kcompute(const unsigned short* Ab, const unsigned short* Bb,
    int rowA0, int rowB0, int l15, int lhi, f4v acc[4][4]){
  #pragma unroll
  for (int ksub=0; ksub<2; ++ksub){
    const int kb = ksub*64 + lhi*16;             // byte offset in 128B row
    bf8v aF[4], bF[4];
    #pragma unroll
    for (int t=0; t<4; ++t){
      const int ra = rowA0 + t*16 + l15;
      aF[t] = *(const bf8v*)((const char*)Ab + ra*128 + (kb ^ ((ra&7)<<4)));
      const int rb = rowB0 + t*16 + l15;
      bF[t] = *(const bf8v*)((const char*)Bb + rb*128 + (kb ^ ((rb&7)<<4)));
    }
    __builtin_amdgcn_s_setprio(1);
    #pragma unroll
    for (int mt=0; mt<4; ++mt)
      #pragma unroll
      for (int nt=0; nt<4; ++nt)
        acc[mt][nt] = __builtin_amdgcn_mfma_f32_16x16x32_bf16(aF[mt], bF[nt], acc[mt][nt], 0,0,0);
    __builtin_amdgcn_s_setprio(0);
  }
}

// ---------- layer 1: M=16384, N=4096 (n=p*256+k), K=512 ----------
// BM=BN=128, BK=64, 256 thr = 4 waves (2M x 2N), wave 64x64, acc[4][4].
// Single-buffered 32KB stage; 33.8KB LDS total (pad-132 bounce) -> 4 blocks/CU.
__global__ __launch_bounds__(256, 4) void l1_kernel(const float* __restrict__ ws,
                                                   const float* __restrict__ head_b,
                                                   const float* __restrict__ b1){
  __shared__ __align__(16) unsigned short lds[128*BPAD];  // 33792 B
  const int bid = blockIdx.x;
  const int xcd = bid & 7, i = bid >> 3;         // i in [0,512)
  const int n0 = (xcd*4 + (i&3)) * 128;          // 4 n-tiles/XCD (L2-resident B)
  const int m0 = (i >> 2) * 128;
  const int p = n0 >> 8;
  const int b = m0 >> 11;
  const int tid = threadIdx.x, w = tid >> 6, lane = tid & 63;
  const int wm = w >> 1, wn = w & 1, l15 = lane & 15, lhi = lane >> 4;
  const unsigned short* gA = g_hidden + (size_t)m0 * H_;
  const unsigned short* gB = g_w1t + (size_t)n0 * H_;

  f4v acc[4][4];
  #pragma unroll
  for (int a=0;a<4;++a)
    #pragma unroll
    for (int c=0;c<4;++c) acc[a][c] = {0.f,0.f,0.f,0.f};

  for (int kt = 0; kt < 8; ++kt){
    stage128(lds,        gA, H_, kt*64, tid);
    stage128(lds + 8192, gB, H_, kt*64, tid);
    __syncthreads();
    kcompute(lds, lds + 8192, wm*64, wn*64, l15, lhi, acc);
    __syncthreads();
  }

  // inline softmax -> prob for this block's expert p
  float lg[P_], inv;
  softmax16(ws, head_b, b, lg, &inv);
  const float prob = lg[p] * inv;

  // epilogue: gelu*prob -> bf16 -> pad-132 LDS bounce (conflict-free) -> 16B stores
  #pragma unroll
  for (int nt=0; nt<4; ++nt){
    const int col = wn*64 + nt*16 + l15;
    const float bias = ws[128 + n0 + col] + b1[n0 + col];
    #pragma unroll
    for (int mt=0; mt<4; ++mt){
      const int r0 = wm*64 + mt*16 + lhi*4;
      unsigned int u01 = pk2bf(gelu_prob(acc[mt][nt][0] + bias, prob),
                               gelu_prob(acc[mt][nt][1] + bias, prob));
      unsigned int u23 = pk2bf(gelu_prob(acc[mt][nt][2] + bias, prob),
                               gelu_prob(acc[mt][nt][3] + bias, prob));
      lds[(r0+0)*BPAD + col] = (unsigned short)(u01 & 0xffffu);
      lds[(r0+1)*BPAD + col] = (unsigned short)(u01 >> 16);
      lds[(r0+2)*BPAD + col] = (unsigned short)(u23 & 0xffffu);
      lds[(r0+3)*BPAD + col] = (unsigned short)(u23 >> 16);
    }
  }
  __syncthreads();
  const int cc = tid & 15, rr = tid >> 4;        // 16 cols x 16 rows per sweep
  #pragma unroll
  for (int pass=0; pass<8; ++pass){
    const int row = pass*16 + rr;
    bf8v vv = *(const bf8v*)&lds[row*BPAD + cc*8];
    *(bf8v*)&g_mid[(size_t)(m0+row)*KCAT + n0 + cc*8] = vv;
  }
}

// ---------- layer 2: out = mid @ w2cat^T + probs.b2 : M=16384, N=512, K=4096 ----------
// BM=BN=128, BK=64, 256 thr, wave 64x64. Dbuf 64KB, counted-vmcnt 2-phase (r12).
__global__ __launch_bounds__(256, 2) void l2_kernel(float* __restrict__ out,
                                                   const float* __restrict__ b2,
                                                   const float* __restrict__ ws,
                                                   const float* __restrict__ head_b){
  __shared__ __align__(16) unsigned short lds[4*128*64];  // 64 KiB: A0,A1,B0,B1
  const int bid = blockIdx.x;
  const int xcd = bid & 7, i = bid >> 3;         // i in [0,64)
  const int n0 = (i & 3) * 128;
  const int m0 = (xcd*16 + (i >> 2)) * 128;
  const int b = m0 >> 11;
  const int tid = threadIdx.x, w = tid >> 6, lane = tid & 63;
  const int wm = w >> 1, wn = w & 1, l15 = lane & 15, lhi = lane >> 4;
  const unsigned short* gA = g_mid + (size_t)m0 * KCAT;
  const unsigned short* gB = g_w2cat + (size_t)n0 * KCAT;

  f4v acc[4][4];
  #pragma unroll
  for (int a=0;a<4;++a)
    #pragma unroll
    for (int c=0;c<4;++c) acc[a][c] = {0.f,0.f,0.f,0.f};

  stage128(lds + 0,     gA, KCAT, 0, tid);       // tile 0 -> buf0
  stage128(lds + 16384, gB, KCAT, 0, tid);
  for (int kt = 0; kt < 64; ++kt){
    const int cur = kt & 1;
    if (kt < 63){                                 // issue tile kt+1 into buf^1
      stage128(lds + (cur ? 0 : 8192),         gA, KCAT, (kt+1)*64, tid);
      stage128(lds + 16384 + (cur ? 0 : 8192), gB, KCAT, (kt+1)*64, tid);
      asm volatile("s_waitcnt vmcnt(8)" ::: "memory");   // current tile landed; next in flight
    } else {
      asm volatile("s_waitcnt vmcnt(0)" ::: "memory");
    }
    __builtin_amdgcn_s_barrier();                 // all waves: current tile in LDS
    kcompute(lds + (cur ? 8192 : 0), lds + 16384 + (cur ? 8192 : 0),
             wm*64, wn*64, l15, lhi, acc);
    __builtin_amdgcn_s_barrier();                 // reads done before buf reuse next iter
  }

  // inline softmax -> full prob vector; bias2w inline
  float lg[P_], inv;
  softmax16(ws, head_b, b, lg, &inv);

  #pragma unroll
  for (int nt=0; nt<4; ++nt){
    const int col = n0 + wn*64 + nt*16 + l15;
    float extra = 0.0f;
    #pragma unroll
    for (int pp=0; pp<P_; ++pp) extra = fmaf(lg[pp]*inv, b2[pp*H_ + col], extra);
    #pragma unroll
    for (int mt=0; mt<4; ++mt){
      #pragma unroll
      for (int j=0;j<4;++j){
        const int row = m0 + wm*64 + mt*16 + lhi*4 + j;
        out[(size_t)row*H_ + col] = acc[mt][nt][j] + extra;
      }
    }
  }
}

extern "C" void kernel_launch(void* const* d_in, const int* in_sizes, int n_in,
                              void* d_out, int out_size, void* d_ws, size_t ws_size,
                              hipStream_t stream){
  const float* hidden = (const float*)d_in[0];
  const float* head_w = (const float*)d_in[1];
  const float* head_b = (const float*)d_in[2];
  const float* embeds = (const float*)d_in[3];
  const float* w1     = (const float*)d_in[4];
  const float* b1     = (const float*)d_in[5];
  const float* w2     = (const float*)d_in[6];
  const float* b2     = (const float*)d_in[7];
  float* out = (float*)d_out;
  float* ws  = (float*)d_ws;   // [0..127] logits, [128..4223] bias1 partials
  (void)in_sizes; (void)n_in; (void)out_size; (void)ws_size;

  (void)hipMemsetAsync(ws, 0, (B_*P_ + P_*K_)*sizeof(float), stream);
  prepass  <<<4096 + M_TOT/64, 256, 0, stream>>>(w1, w2, embeds, hidden, head_w, ws);
  l1_kernel<<<4096, 256, 0, stream>>>(ws, head_b, b1);
  l2_kernel<<<512, 256, 0, stream>>>(out, b2, ws, head_b);
}